// Round 10
// baseline (100.261 us; speedup 1.0000x reference)
//
#include <hip/hip_runtime.h>
#include <cmath>

typedef short bf16x8 __attribute__((ext_vector_type(8)));
typedef short bf16x4 __attribute__((ext_vector_type(4)));
typedef float f32x4 __attribute__((ext_vector_type(4)));

namespace {
constexpr int kN   = 16;
constexpr int kC   = 128;
constexpr int kH   = 48;
constexpr int kW   = 48;
constexpr int kHW  = kH * kW;      // 2304
constexpr int kK9  = 192;          // 3*C/2
constexpr int kNPC = 18;           // correlation p-chunks
constexpr int kPCH = kHW / kNPC;   // 128
constexpr int kLS  = 132;          // LDS row stride (floats) for fp32 transpose tile
constexpr int kPA  = 136;          // bf16 LDS stride (272B, 16B-aligned)
}

__device__ __forceinline__ unsigned short f2b(float f) {
  unsigned u = __builtin_bit_cast(unsigned, f);
  u = (u + 0x7FFFu + ((u >> 16) & 1u)) >> 16;   // RTNE
  return (unsigned short)u;
}
__device__ __forceinline__ float b2f(unsigned short u) {
  return __builtin_bit_cast(float, ((unsigned)u) << 16);
}

// LDS index for fp32 transpose tile: [w][c] with XOR swizzle on the c-octet.
__device__ __forceinline__ int tidx(int w, int c) {
  return w * kLS + (c ^ (((w >> 2) & 3) << 3));
}

// ---------------------------------------------------------------------------
// Fused prep: blocks 0..47 p5T transpose; 48..111 w6->bf16; 112..119 Weff;
// block 119 also zeroes the per-n completion counters (used by k_corr).
// ---------------------------------------------------------------------------
__global__ __launch_bounds__(256)
void k_prep(const float* __restrict__ p5, const float* __restrict__ w6,
            const float* __restrict__ w10, const float* __restrict__ w8,
            float* __restrict__ p5T, unsigned short* __restrict__ w6b,
            float* __restrict__ Weff, int* __restrict__ cnt) {
  const int tid = threadIdx.x;
  const int bb = blockIdx.x;
  if (bb < 48) {                     // p5T[q][c] = p5[c][q]
    __shared__ float Ls[kW * kLS];
    const int h = bb;
    for (int i = 0; i < 6; ++i) {
      const int idx = i * 256 + tid;
      const int c = idx / 12, s = idx % 12;
      const float4 v = *(const float4*)(p5 + (size_t)c * kHW + h * kW + s * 4);
      const int sw = (s & 3) << 3;
      Ls[(4 * s + 0) * kLS + (c ^ sw)] = v.x;
      Ls[(4 * s + 1) * kLS + (c ^ sw)] = v.y;
      Ls[(4 * s + 2) * kLS + (c ^ sw)] = v.z;
      Ls[(4 * s + 3) * kLS + (c ^ sw)] = v.w;
    }
    __syncthreads();
    for (int i = 0; i < 3; ++i) {
      const int idx = i * 256 + tid;
      const int w = idx >> 4, c = (idx & 15) * 8;
      const float* s = &Ls[tidx(w, c)];
      float4 a{s[0], s[1], s[2], s[3]}, b{s[4], s[5], s[6], s[7]};
      float* dst = p5T + ((size_t)(h * kW + w)) * kC + c;
      *(float4*)dst = a;
      *(float4*)(dst + 4) = b;
    }
  } else if (bb < 112) {             // w6 -> bf16
    const int i = (bb - 48) * 256 + tid;
    w6b[i] = f2b(w6[i]);
  } else {                           // Weff[o][kk*5+j]
    const int idx = (bb - 112) * 256 + tid;
    if (idx < kC * 15) {
      const int o = idx / 15, t = idx - o * 15;
      const int kk = t / 5, j = t - kk * 5;
      float s = 0.f;
#pragma unroll
      for (int c2 = 0; c2 < 64; ++c2)
        s = fmaf(w10[o * kK9 + 3 * c2 + kk], w8[c2 * 5 + j], s);
      Weff[idx] = s;
    }
    if (bb == 119 && tid < kN) cnt[tid] = 0;   // reset completion counters
  }
}

// ---------------------------------------------------------------------------
// Fused transpose + t6 GEMM. One block per (n,h). Linear barrier structure.
// w6 A-fragments read directly from global (L2-resident) -> 38.4 KB LDS,
// 4 blocks/CU. Emits xT [q][c], xB [c][q] bf16, t1, t6.
// ---------------------------------------------------------------------------
__global__ __launch_bounds__(256)
void k_xt5t6(const float* __restrict__ x, const float* __restrict__ p5T,
             const unsigned short* __restrict__ w6b,
             unsigned short* __restrict__ xT, unsigned short* __restrict__ xB,
             float* __restrict__ t1, unsigned short* __restrict__ t6) {
  __shared__ __align__(16) float Ls[kW * kLS];             // 25.3 KB
  __shared__ __align__(16) unsigned short t5s[kW * kPA];   // 13.1 KB
  const int b = blockIdx.x;                  // n*48 + h
  const int n = b / kH, h = b - n * kH;
  const int tid = threadIdx.x;
  const float* xrow = x + (size_t)n * kC * kHW + h * kW;
  unsigned short* xBrow = xB + (size_t)n * kC * kHW + h * kW;
  // phase 1: stage x tile (coalesced); emit xB bf16 [c][q]
  for (int i = 0; i < 6; ++i) {
    const int idx = i * 256 + tid;
    const int c = idx / 12, s = idx % 12;
    const float4 v = *(const float4*)(xrow + (size_t)c * kHW + s * 4);
    const int sw = (s & 3) << 3;
    Ls[(4 * s + 0) * kLS + (c ^ sw)] = v.x;
    Ls[(4 * s + 1) * kLS + (c ^ sw)] = v.y;
    Ls[(4 * s + 2) * kLS + (c ^ sw)] = v.z;
    Ls[(4 * s + 3) * kLS + (c ^ sw)] = v.w;
    bf16x4 xb4{(short)f2b(v.x), (short)f2b(v.y), (short)f2b(v.z), (short)f2b(v.w)};
    *(bf16x4*)(xBrow + (size_t)c * kHW + s * 4) = xb4;
  }
  __syncthreads();

  // phase 2: xT + t5s + t1
  for (int i = 0; i < 3; ++i) {
    const int idx = i * 256 + tid;
    const int w = idx >> 4, c = (idx & 15) * 8;
    const int wp = (w == 0) ? (kW - 1) : (w - 1);
    const float* sv = &Ls[tidx(w, c)];
    const float* sp = &Ls[tidx(wp, c)];
    const int q = h * kW + w;
    const float* pv = p5T + (size_t)q * kC + c;

    unsigned short xb[8], tb[8];
    float m = -3.4e38f;
#pragma unroll
    for (int j = 0; j < 8; ++j) {
      const float xv = sv[j];
      const float t5 = pv[j] * fmaxf(-xv, -sp[j]);
      xb[j] = f2b(xv);
      tb[j] = f2b(t5);
      m = fmaxf(m, xv);
    }
    *(bf16x8*)(xT + ((size_t)n * kHW + q) * kC + c) = *(const bf16x8*)xb;
    *(bf16x8*)&t5s[w * kPA + c] = *(const bf16x8*)tb;
#pragma unroll
    for (int off = 1; off < 16; off <<= 1)
      m = fmaxf(m, __shfl_xor(m, off, 16));
    if ((tid & 15) == 0) t1[(size_t)n * kHW + q] = m;
  }
  __syncthreads();

  // phase 3: t6 = w6 @ t5  (m=128 o, n=48 q, k=128 c); A direct from global
  const int wv = tid >> 6, lane = tid & 63;
  const int lr = lane & 15, lk = (lane >> 4) * 8;
  f32x4 acc[2][3];
#pragma unroll
  for (int i = 0; i < 2; ++i)
#pragma unroll
    for (int j = 0; j < 3; ++j) acc[i][j] = f32x4{0.f, 0.f, 0.f, 0.f};
#pragma unroll
  for (int ks = 0; ks < kC; ks += 32) {
    bf16x8 a[2], bf[3];
#pragma unroll
    for (int mt = 0; mt < 2; ++mt)
      a[mt] = *(const bf16x8*)(w6b + (size_t)(32 * wv + 16 * mt + lr) * kC + ks + lk);
#pragma unroll
    for (int nt = 0; nt < 3; ++nt)
      bf[nt] = *(const bf16x8*)&t5s[(16 * nt + lr) * kPA + ks + lk];
#pragma unroll
    for (int mt = 0; mt < 2; ++mt)
#pragma unroll
      for (int nt = 0; nt < 3; ++nt)
        acc[mt][nt] = __builtin_amdgcn_mfma_f32_16x16x32_bf16(a[mt], bf[nt], acc[mt][nt], 0, 0, 0);
  }
#pragma unroll
  for (int mt = 0; mt < 2; ++mt)
#pragma unroll
    for (int nt = 0; nt < 3; ++nt) {
      const int q = h * kW + 16 * nt + lr;
#pragma unroll
      for (int r = 0; r < 4; ++r) {
        const int o = 32 * wv + 16 * mt + 4 * (lane >> 4) + r;
        t6[((size_t)n * kC + o) * kHW + q] = f2b(acc[mt][nt][r]);
      }
    }
}

// ---------------------------------------------------------------------------
// Fused t8..t12 + correlation partials + last-block-per-n reduction -> M.
// Race-free linear structure: stage -> sync -> t12 build -> sync -> MFMA.
// Cross-block: producer fence+atomicAdd; 18th block for n reduces in fixed
// chunk order (bitwise-deterministic, same math as the old k_redM).
// ---------------------------------------------------------------------------
__global__ __launch_bounds__(256)
void k_corr(const unsigned short* __restrict__ xB, const float* __restrict__ t1,
            const float* __restrict__ Weff, const unsigned short* __restrict__ t6,
            unsigned short* __restrict__ part, unsigned short* __restrict__ M,
            int* __restrict__ cnt) {
  __shared__ __align__(16) unsigned short t12s[kC * kPA];   // 34.8 KB
  __shared__ __align__(16) unsigned short Bsf[kC * kPA];    // 34.8 KB
  __shared__ __align__(16) float t1s[8 * 60];               // 1.9 KB
  __shared__ float sW[kC][15];                              // 7.5 KB
  const int tid = threadIdx.x;
  const int n = blockIdx.y;
  const int chunk = blockIdx.x;
  const int p0 = chunk * kPCH;
  const int h_lo = p0 / kW;
  const unsigned short* Bg = t6 + (size_t)n * kC * kHW + p0;

  // ---- stage phase (LDS writes only) ----
  for (int i = tid; i < 8 * 60; i += 256) {
    const int r = i / 60, cc = i - r * 60;
    const int hh = h_lo - 2 + r, ww = cc - 6;
    t1s[i] = (hh >= 0 && hh < kH && ww >= 0 && ww < kW) ? t1[n * kHW + hh * kW + ww] : 0.f;
  }
  for (int i = tid; i < kC * 15; i += 256) {
    const int c = i / 15, t = i - c * 15;
    sW[c][t] = Weff[((c - 1) & (kC - 1)) * 15 + t];        // channel roll
  }
#pragma unroll
  for (int i = 0; i < 8; ++i) {
    const int f = i * 256 + tid;
    const int c = f >> 4, seg = (f & 15) * 8;
    *(bf16x8*)&Bsf[c * kPA + seg] = *(const bf16x8*)(Bg + (size_t)c * kHW + seg);
  }
  __syncthreads();

  // ---- t12 tile build (reads t1s/sW/xB; writes disjoint t12s cells) ----
  const unsigned short* xn = xB + (size_t)n * kC * kHW;
  for (int it = 0; it < 8; ++it) {
    const int idx = it * 256 + tid;
    const int c = idx >> 4, p = (idx & 15) * 8;
    const int q = p0 + p;
    const int h = q / kW, w0 = q - h * kW;                 // w0 multiple of 8
    const int r0 = h - h_lo;                               // t1s row for kk=0
    float tap[3][20];
#pragma unroll
    for (int kk = 0; kk < 3; ++kk) {
      const float* src = &t1s[(r0 + 2 * kk) * 60 + w0];
#pragma unroll
      for (int j4 = 0; j4 < 5; ++j4) {
        const float4 v = *(const float4*)(src + 4 * j4);
        tap[kk][4 * j4 + 0] = v.x; tap[kk][4 * j4 + 1] = v.y;
        tap[kk][4 * j4 + 2] = v.z; tap[kk][4 * j4 + 3] = v.w;
      }
    }
    float wr[15];
#pragma unroll
    for (int t = 0; t < 15; ++t) wr[t] = sW[c][t];
    const bf16x8 xv8 = *(const bf16x8*)(xn + (size_t)c * kHW + q);
    unsigned short o16[8];
#pragma unroll
    for (int dp = 0; dp < 8; ++dp) {
      float acc = 0.f;
#pragma unroll
      for (int kk = 0; kk < 3; ++kk)
#pragma unroll
        for (int j = 0; j < 5; ++j)
          acc = fmaf(wr[kk * 5 + j], tap[kk][3 * j + dp], acc);
      o16[dp] = f2b(fmaxf(b2f((unsigned short)xv8[dp]), acc));
    }
    *(bf16x8*)&t12s[c * kPA + p] = *(const bf16x8*)o16;
  }
  __syncthreads();

  // ---- MFMA: part[c][c'] = sum_p t12[c][p] * t6[c'][p]  (pure reads) ----
  const int wv = tid >> 6, lane = tid & 63;
  const int lr = lane & 15, lk = (lane >> 4) * 8;
  const int wr2 = (wv >> 1) * 64, wc2 = (wv & 1) * 64;
  f32x4 acc[4][4];
#pragma unroll
  for (int i = 0; i < 4; ++i)
#pragma unroll
    for (int j = 0; j < 4; ++j) acc[i][j] = f32x4{0.f, 0.f, 0.f, 0.f};

#pragma unroll
  for (int ks = 0; ks < kPCH; ks += 32) {
    bf16x8 a[4], bv[4];
#pragma unroll
    for (int i = 0; i < 4; ++i) {
      a[i]  = *(const bf16x8*)&t12s[(wr2 + 16 * i + lr) * kPA + ks + lk];
      bv[i] = *(const bf16x8*)&Bsf[(wc2 + 16 * i + lr) * kPA + ks + lk];
    }
#pragma unroll
    for (int i = 0; i < 4; ++i)
#pragma unroll
      for (int j = 0; j < 4; ++j)
        acc[i][j] = __builtin_amdgcn_mfma_f32_16x16x32_bf16(a[i], bv[j], acc[i][j], 0, 0, 0);
  }

  unsigned short* dst = part + ((size_t)chunk * kN + n) * (kC * kC);
#pragma unroll
  for (int i = 0; i < 4; ++i)
#pragma unroll
    for (int j = 0; j < 4; ++j)
#pragma unroll
      for (int r = 0; r < 4; ++r)
        dst[(wr2 + 16 * i + 4 * (lane >> 4) + r) * kC + wc2 + 16 * j + lr] = f2b(acc[i][j][r]);

  // ---- completion: last block for this n reduces all 18 slabs -> M[n] ----
  __threadfence();                                         // release part writes
  __shared__ int isLast;
  if (tid == 0) isLast = (atomicAdd(&cnt[n], 1) == kNPC - 1);
  __syncthreads();
  if (isLast) {
    __threadfence();                                       // acquire others' writes
#pragma unroll
    for (int jb = 0; jb < 8; ++jb) {
      const int r0 = (jb * 256 + tid) * 8;                 // 0..16383 step 8
      float acc8[8];
#pragma unroll
      for (int e = 0; e < 8; ++e) acc8[e] = 0.f;
#pragma unroll
      for (int ch = 0; ch < kNPC; ++ch) {
        const bf16x8 v = *(const bf16x8*)(part + (((size_t)ch * kN + n) << 14) + r0);
#pragma unroll
        for (int e = 0; e < 8; ++e) acc8[e] += b2f((unsigned short)v[e]);
      }
      unsigned short o16[8];
#pragma unroll
      for (int e = 0; e < 8; ++e) o16[e] = f2b(acc8[e]);
      *(bf16x8*)(M + ((size_t)n << 14) + r0) = *(const bf16x8*)o16;
    }
  }
}

// ---------------------------------------------------------------------------
// Final GEMM: out[n,m,q] = scale * sum_k M[n,m,k] * xT[n,q,k].
// A-fragments direct from global (M is 32 KB/n, L2-hot) -> 17.4 KB LDS.
// Race-free: stage Bs -> ONE sync -> barrier-free compute.
// ---------------------------------------------------------------------------
__global__ __launch_bounds__(256)
void k_out(const unsigned short* __restrict__ A, const unsigned short* __restrict__ B,
           float* __restrict__ Out, float scale) {
  constexpr int K = 128;
  __shared__ __align__(16) unsigned short Bs[64 * kPA];    // 17.4 KB
  const int tid = threadIdx.x;
  const int n = blockIdx.y;
  const int qbase = blockIdx.x * 64;
  const unsigned short* Ag = A + (size_t)n * kC * K;
  const unsigned short* Bg = B + ((size_t)n * kHW + qbase) * K;

#pragma unroll
  for (int i = 0; i < 4; ++i) {
    const int f = i * 256 + tid;
    const int q = f >> 4, seg = (f & 15) * 8;
    *(bf16x8*)&Bs[q * kPA + seg] = *(const bf16x8*)(Bg + (size_t)q * K + seg);
  }
  __syncthreads();

  const int wv = tid >> 6, lane = tid & 63;
  const int lr = lane & 15, lk = (lane >> 4) * 8;

  f32x4 acc[2][4];
#pragma unroll
  for (int i = 0; i < 2; ++i)
#pragma unroll
    for (int j = 0; j < 4; ++j) acc[i][j] = f32x4{0.f, 0.f, 0.f, 0.f};

#pragma unroll
  for (int ks = 0; ks < K; ks += 32) {
    bf16x8 a[2], b[4];
#pragma unroll
    for (int mt = 0; mt < 2; ++mt)
      a[mt] = *(const bf16x8*)(Ag + (size_t)(32 * wv + 16 * mt + lr) * K + ks + lk);
#pragma unroll
    for (int nt = 0; nt < 4; ++nt)
      b[nt] = *(const bf16x8*)&Bs[(16 * nt + lr) * kPA + ks + lk];
#pragma unroll
    for (int mt = 0; mt < 2; ++mt)
#pragma unroll
      for (int nt = 0; nt < 4; ++nt)
        acc[mt][nt] = __builtin_amdgcn_mfma_f32_16x16x32_bf16(
            a[mt], b[nt], acc[mt][nt], 0, 0, 0);
  }

#pragma unroll
  for (int mt = 0; mt < 2; ++mt)
#pragma unroll
    for (int nt = 0; nt < 4; ++nt) {
      const int q = qbase + 16 * nt + lr;
#pragma unroll
      for (int r = 0; r < 4; ++r) {
        const int m = 32 * wv + 16 * mt + 4 * (lane >> 4) + r;
        Out[((size_t)n * kC + m) * kHW + q] = scale * acc[mt][nt][r];
      }
    }
}

// ---------------------------------------------------------------------------
extern "C" void kernel_launch(void* const* d_in, const int* in_sizes, int n_in,
                              void* d_out, int out_size, void* d_ws, size_t ws_size,
                              hipStream_t stream) {
  const float* x   = (const float*)d_in[0];
  const float* p5  = (const float*)d_in[1];
  const float* w6  = (const float*)d_in[2];
  const float* w8  = (const float*)d_in[3];
  const float* w10 = (const float*)d_in[4];
  float* out = (float*)d_out;

  char* ws = (char*)d_ws;                                  // byte offsets
  unsigned short* xT   = (unsigned short*)(ws);            //  9,437,184
  unsigned short* t6b  = (unsigned short*)(ws + 9437184);  //  9,437,184
  unsigned short* part = (unsigned short*)(ws + 18874368); //  9,437,184 (bf16)
  unsigned short* xB   = (unsigned short*)(ws + 28311552); //  9,437,184
  unsigned short* Mb   = (unsigned short*)(ws + 37748736); //    524,288
  float*          t1b  = (float*)(ws + 38273024);          //    147,456
  unsigned short* w6b  = (unsigned short*)(ws + 38420480); //     32,768
  float*          Weff = (float*)(ws + 38453248);          //      7,680
  float*          p5T  = (float*)(ws + 38460928);          //  1,179,648
  int*            cnt  = (int*)(ws + 39640576);            //         64 (end ~39.6 MB)

  const float scale = 1.0f / (sqrtf((float)kC) * sqrtf((float)kHW));

  k_prep<<<120, 256, 0, stream>>>(p5, w6, w10, w8, p5T, w6b, Weff, cnt);
  k_xt5t6<<<kN * kH, 256, 0, stream>>>(x, p5T, w6b, xT, xB, t1b, t6b);
  k_corr<<<dim3(kNPC, kN), 256, 0, stream>>>(xB, t1b, Weff, t6b, part, Mb, cnt);
  k_out<<<dim3(kHW / 64, kN), 256, 0, stream>>>(Mb, xT, out, scale);
}

// Round 11
// 47.672 us; speedup vs baseline: 2.1032x; 2.1032x over previous
//
#include <hip/hip_runtime.h>
#include <cmath>

typedef short bf16x8 __attribute__((ext_vector_type(8)));
typedef short bf16x4 __attribute__((ext_vector_type(4)));
typedef float f32x4 __attribute__((ext_vector_type(4)));

namespace {
constexpr int kN   = 16;
constexpr int kC   = 128;
constexpr int kH   = 48;
constexpr int kW   = 48;
constexpr int kHW  = kH * kW;      // 2304
constexpr int kK9  = 192;          // 3*C/2
constexpr int kNPC = 18;           // correlation p-chunks
constexpr int kPCH = kHW / kNPC;   // 128
constexpr int kLS  = 132;          // LDS row stride (floats) for fp32 transpose tile
constexpr int kPA  = 136;          // bf16 LDS stride (272B, 16B-aligned)
}

__device__ __forceinline__ unsigned short f2b(float f) {
  unsigned u = __builtin_bit_cast(unsigned, f);
  u = (u + 0x7FFFu + ((u >> 16) & 1u)) >> 16;   // RTNE
  return (unsigned short)u;
}
__device__ __forceinline__ float b2f(unsigned short u) {
  return __builtin_bit_cast(float, ((unsigned)u) << 16);
}

// LDS index for fp32 transpose tile: [w][c] with XOR swizzle on the c-octet.
__device__ __forceinline__ int tidx(int w, int c) {
  return w * kLS + (c ^ (((w >> 2) & 3) << 3));
}

// ---------------------------------------------------------------------------
// Fused prep: blocks 0..47 p5T transpose; 48..111 w6->bf16; 112..119 Weff.
// ---------------------------------------------------------------------------
__global__ __launch_bounds__(256)
void k_prep(const float* __restrict__ p5, const float* __restrict__ w6,
            const float* __restrict__ w10, const float* __restrict__ w8,
            float* __restrict__ p5T, unsigned short* __restrict__ w6b,
            float* __restrict__ Weff) {
  const int tid = threadIdx.x;
  const int bb = blockIdx.x;
  if (bb < 48) {                     // p5T[q][c] = p5[c][q]
    __shared__ float Ls[kW * kLS];
    const int h = bb;
    for (int i = 0; i < 6; ++i) {
      const int idx = i * 256 + tid;
      const int c = idx / 12, s = idx % 12;
      const float4 v = *(const float4*)(p5 + (size_t)c * kHW + h * kW + s * 4);
      const int sw = (s & 3) << 3;
      Ls[(4 * s + 0) * kLS + (c ^ sw)] = v.x;
      Ls[(4 * s + 1) * kLS + (c ^ sw)] = v.y;
      Ls[(4 * s + 2) * kLS + (c ^ sw)] = v.z;
      Ls[(4 * s + 3) * kLS + (c ^ sw)] = v.w;
    }
    __syncthreads();
    for (int i = 0; i < 3; ++i) {
      const int idx = i * 256 + tid;
      const int w = idx >> 4, c = (idx & 15) * 8;
      const float* s = &Ls[tidx(w, c)];
      float4 a{s[0], s[1], s[2], s[3]}, b{s[4], s[5], s[6], s[7]};
      float* dst = p5T + ((size_t)(h * kW + w)) * kC + c;
      *(float4*)dst = a;
      *(float4*)(dst + 4) = b;
    }
  } else if (bb < 112) {             // w6 -> bf16
    const int i = (bb - 48) * 256 + tid;
    w6b[i] = f2b(w6[i]);
  } else {                           // Weff[o][kk*5+j]
    const int idx = (bb - 112) * 256 + tid;
    if (idx < kC * 15) {
      const int o = idx / 15, t = idx - o * 15;
      const int kk = t / 5, j = t - kk * 5;
      float s = 0.f;
#pragma unroll
      for (int c2 = 0; c2 < 64; ++c2)
        s = fmaf(w10[o * kK9 + 3 * c2 + kk], w8[c2 * 5 + j], s);
      Weff[idx] = s;
    }
  }
}

// ---------------------------------------------------------------------------
// Fused transpose + t6 GEMM. One block per (n,h). Linear barrier structure.
// w6 A-fragments read directly from global (32 KB, L2-resident, shared by all
// 768 blocks) -> LDS 38.4 KB -> 4 blocks/CU.
// ---------------------------------------------------------------------------
__global__ __launch_bounds__(256)
void k_xt5t6(const float* __restrict__ x, const float* __restrict__ p5T,
             const unsigned short* __restrict__ w6b,
             unsigned short* __restrict__ xT, unsigned short* __restrict__ xB,
             float* __restrict__ t1, unsigned short* __restrict__ t6) {
  __shared__ __align__(16) float Ls[kW * kLS];             // 25.3 KB
  __shared__ __align__(16) unsigned short t5s[kW * kPA];   // 13.1 KB
  const int b = blockIdx.x;                  // n*48 + h
  const int n = b / kH, h = b - n * kH;
  const int tid = threadIdx.x;
  const float* xrow = x + (size_t)n * kC * kHW + h * kW;
  unsigned short* xBrow = xB + (size_t)n * kC * kHW + h * kW;
  // phase 1: stage x tile (coalesced); emit xB bf16 [c][q]
  for (int i = 0; i < 6; ++i) {
    const int idx = i * 256 + tid;
    const int c = idx / 12, s = idx % 12;
    const float4 v = *(const float4*)(xrow + (size_t)c * kHW + s * 4);
    const int sw = (s & 3) << 3;
    Ls[(4 * s + 0) * kLS + (c ^ sw)] = v.x;
    Ls[(4 * s + 1) * kLS + (c ^ sw)] = v.y;
    Ls[(4 * s + 2) * kLS + (c ^ sw)] = v.z;
    Ls[(4 * s + 3) * kLS + (c ^ sw)] = v.w;
    bf16x4 xb4{(short)f2b(v.x), (short)f2b(v.y), (short)f2b(v.z), (short)f2b(v.w)};
    *(bf16x4*)(xBrow + (size_t)c * kHW + s * 4) = xb4;
  }
  __syncthreads();

  // phase 2: xT + t5s + t1
  for (int i = 0; i < 3; ++i) {
    const int idx = i * 256 + tid;
    const int w = idx >> 4, c = (idx & 15) * 8;
    const int wp = (w == 0) ? (kW - 1) : (w - 1);
    const float* sv = &Ls[tidx(w, c)];
    const float* sp = &Ls[tidx(wp, c)];
    const int q = h * kW + w;
    const float* pv = p5T + (size_t)q * kC + c;

    unsigned short xb[8], tb[8];
    float m = -3.4e38f;
#pragma unroll
    for (int j = 0; j < 8; ++j) {
      const float xv = sv[j];
      const float t5 = pv[j] * fmaxf(-xv, -sp[j]);
      xb[j] = f2b(xv);
      tb[j] = f2b(t5);
      m = fmaxf(m, xv);
    }
    *(bf16x8*)(xT + ((size_t)n * kHW + q) * kC + c) = *(const bf16x8*)xb;
    *(bf16x8*)&t5s[w * kPA + c] = *(const bf16x8*)tb;
#pragma unroll
    for (int off = 1; off < 16; off <<= 1)
      m = fmaxf(m, __shfl_xor(m, off, 16));
    if ((tid & 15) == 0) t1[(size_t)n * kHW + q] = m;
  }
  __syncthreads();

  // phase 3: t6 = w6 @ t5  (m=128 o, n=48 q, k=128 c); A direct from global
  const int wv = tid >> 6, lane = tid & 63;
  const int lr = lane & 15, lk = (lane >> 4) * 8;
  f32x4 acc[2][3];
#pragma unroll
  for (int i = 0; i < 2; ++i)
#pragma unroll
    for (int j = 0; j < 3; ++j) acc[i][j] = f32x4{0.f, 0.f, 0.f, 0.f};
#pragma unroll
  for (int ks = 0; ks < kC; ks += 32) {
    bf16x8 a[2], bf[3];
#pragma unroll
    for (int mt = 0; mt < 2; ++mt)
      a[mt] = *(const bf16x8*)(w6b + (size_t)(32 * wv + 16 * mt + lr) * kC + ks + lk);
#pragma unroll
    for (int nt = 0; nt < 3; ++nt)
      bf[nt] = *(const bf16x8*)&t5s[(16 * nt + lr) * kPA + ks + lk];
#pragma unroll
    for (int mt = 0; mt < 2; ++mt)
#pragma unroll
      for (int nt = 0; nt < 3; ++nt)
        acc[mt][nt] = __builtin_amdgcn_mfma_f32_16x16x32_bf16(a[mt], bf[nt], acc[mt][nt], 0, 0, 0);
  }
#pragma unroll
  for (int mt = 0; mt < 2; ++mt)
#pragma unroll
    for (int nt = 0; nt < 3; ++nt) {
      const int q = h * kW + 16 * nt + lr;
#pragma unroll
      for (int r = 0; r < 4; ++r) {
        const int o = 32 * wv + 16 * mt + 4 * (lane >> 4) + r;
        t6[((size_t)n * kC + o) * kHW + q] = f2b(acc[mt][nt][r]);
      }
    }
}

// ---------------------------------------------------------------------------
// Fused t8..t12 + correlation partials (bf16 partial output).
// Race-free linear structure: stage -> sync -> t12 build -> sync -> MFMA.
// NO cross-block sync (R10's fence-fusion cost 60us in L2 writebacks).
// ---------------------------------------------------------------------------
__global__ __launch_bounds__(256)
void k_corr(const unsigned short* __restrict__ xB, const float* __restrict__ t1,
            const float* __restrict__ Weff, const unsigned short* __restrict__ t6,
            unsigned short* __restrict__ part) {
  __shared__ __align__(16) unsigned short t12s[kC * kPA];   // 34.8 KB
  __shared__ __align__(16) unsigned short Bsf[kC * kPA];    // 34.8 KB
  __shared__ __align__(16) float t1s[8 * 60];               // 1.9 KB
  __shared__ float sW[kC][15];                              // 7.5 KB
  const int tid = threadIdx.x;
  const int n = blockIdx.y;
  const int chunk = blockIdx.x;
  const int p0 = chunk * kPCH;
  const int h_lo = p0 / kW;
  const unsigned short* Bg = t6 + (size_t)n * kC * kHW + p0;

  // ---- stage phase (LDS writes only) ----
  for (int i = tid; i < 8 * 60; i += 256) {
    const int r = i / 60, cc = i - r * 60;
    const int hh = h_lo - 2 + r, ww = cc - 6;
    t1s[i] = (hh >= 0 && hh < kH && ww >= 0 && ww < kW) ? t1[n * kHW + hh * kW + ww] : 0.f;
  }
  for (int i = tid; i < kC * 15; i += 256) {
    const int c = i / 15, t = i - c * 15;
    sW[c][t] = Weff[((c - 1) & (kC - 1)) * 15 + t];        // channel roll
  }
#pragma unroll
  for (int i = 0; i < 8; ++i) {
    const int f = i * 256 + tid;
    const int c = f >> 4, seg = (f & 15) * 8;
    *(bf16x8*)&Bsf[c * kPA + seg] = *(const bf16x8*)(Bg + (size_t)c * kHW + seg);
  }
  __syncthreads();

  // ---- t12 tile build (reads t1s/sW/xB; writes disjoint t12s cells) ----
  const unsigned short* xn = xB + (size_t)n * kC * kHW;
  for (int it = 0; it < 8; ++it) {
    const int idx = it * 256 + tid;
    const int c = idx >> 4, p = (idx & 15) * 8;
    const int q = p0 + p;
    const int h = q / kW, w0 = q - h * kW;                 // w0 multiple of 8
    const int r0 = h - h_lo;                               // t1s row for kk=0
    float tap[3][20];
#pragma unroll
    for (int kk = 0; kk < 3; ++kk) {
      const float* src = &t1s[(r0 + 2 * kk) * 60 + w0];
#pragma unroll
      for (int j4 = 0; j4 < 5; ++j4) {
        const float4 v = *(const float4*)(src + 4 * j4);
        tap[kk][4 * j4 + 0] = v.x; tap[kk][4 * j4 + 1] = v.y;
        tap[kk][4 * j4 + 2] = v.z; tap[kk][4 * j4 + 3] = v.w;
      }
    }
    float wr[15];
#pragma unroll
    for (int t = 0; t < 15; ++t) wr[t] = sW[c][t];
    const bf16x8 xv8 = *(const bf16x8*)(xn + (size_t)c * kHW + q);
    unsigned short o16[8];
#pragma unroll
    for (int dp = 0; dp < 8; ++dp) {
      float acc = 0.f;
#pragma unroll
      for (int kk = 0; kk < 3; ++kk)
#pragma unroll
        for (int j = 0; j < 5; ++j)
          acc = fmaf(wr[kk * 5 + j], tap[kk][3 * j + dp], acc);
      o16[dp] = f2b(fmaxf(b2f((unsigned short)xv8[dp]), acc));
    }
    *(bf16x8*)&t12s[c * kPA + p] = *(const bf16x8*)o16;
  }
  __syncthreads();

  // ---- MFMA: part[c][c'] = sum_p t12[c][p] * t6[c'][p]  (pure reads) ----
  const int wv = tid >> 6, lane = tid & 63;
  const int lr = lane & 15, lk = (lane >> 4) * 8;
  const int wr2 = (wv >> 1) * 64, wc2 = (wv & 1) * 64;
  f32x4 acc[4][4];
#pragma unroll
  for (int i = 0; i < 4; ++i)
#pragma unroll
    for (int j = 0; j < 4; ++j) acc[i][j] = f32x4{0.f, 0.f, 0.f, 0.f};

#pragma unroll
  for (int ks = 0; ks < kPCH; ks += 32) {
    bf16x8 a[4], bv[4];
#pragma unroll
    for (int i = 0; i < 4; ++i) {
      a[i]  = *(const bf16x8*)&t12s[(wr2 + 16 * i + lr) * kPA + ks + lk];
      bv[i] = *(const bf16x8*)&Bsf[(wc2 + 16 * i + lr) * kPA + ks + lk];
    }
#pragma unroll
    for (int i = 0; i < 4; ++i)
#pragma unroll
      for (int j = 0; j < 4; ++j)
        acc[i][j] = __builtin_amdgcn_mfma_f32_16x16x32_bf16(a[i], bv[j], acc[i][j], 0, 0, 0);
  }

  unsigned short* dst = part + ((size_t)chunk * kN + n) * (kC * kC);
#pragma unroll
  for (int i = 0; i < 4; ++i)
#pragma unroll
    for (int j = 0; j < 4; ++j)
#pragma unroll
      for (int r = 0; r < 4; ++r)
        dst[(wr2 + 16 * i + 4 * (lane >> 4) + r) * kC + wc2 + 16 * j + lr] = f2b(acc[i][j][r]);
}

// ---------------------------------------------------------------------------
// Reduce kNPC bf16 partial slabs -> M bf16 [n][c][c'].  Vectorized bf16x8.
// ---------------------------------------------------------------------------
__global__ __launch_bounds__(256)
void k_redM(const unsigned short* __restrict__ part, unsigned short* __restrict__ M) {
  const int bid = blockIdx.x;                              // 128 blocks
  const int j = bid >> 4, n = bid & 15;
  const int r0 = (j * 256 + threadIdx.x) * 8;              // 0..16383 step 8
  float acc[8];
#pragma unroll
  for (int e = 0; e < 8; ++e) acc[e] = 0.f;
#pragma unroll
  for (int ch = 0; ch < kNPC; ++ch) {
    const bf16x8 v = *(const bf16x8*)(part + (((size_t)ch * kN + n) << 14) + r0);
#pragma unroll
    for (int e = 0; e < 8; ++e) acc[e] += b2f((unsigned short)v[e]);
  }
  unsigned short o16[8];
#pragma unroll
  for (int e = 0; e < 8; ++e) o16[e] = f2b(acc[e]);
  *(bf16x8*)(M + ((size_t)n << 14) + r0) = *(const bf16x8*)o16;
}

// ---------------------------------------------------------------------------
// Final GEMM: out[n,m,q] = scale * sum_k M[n,m,k] * xT[n,q,k].
// A-fragments direct from global (M = 0.5 MB total, L2/L3-hot) -> 17.4 KB LDS.
// Race-free: stage Bs -> ONE sync -> barrier-free compute.
// ---------------------------------------------------------------------------
__global__ __launch_bounds__(256)
void k_out(const unsigned short* __restrict__ A, const unsigned short* __restrict__ B,
           float* __restrict__ Out, float scale) {
  constexpr int K = 128;
  __shared__ __align__(16) unsigned short Bs[64 * kPA];    // 17.4 KB
  const int tid = threadIdx.x;
  const int n = blockIdx.y;
  const int qbase = blockIdx.x * 64;
  const unsigned short* Ag = A + (size_t)n * kC * K;
  const unsigned short* Bg = B + ((size_t)n * kHW + qbase) * K;

#pragma unroll
  for (int i = 0; i < 4; ++i) {
    const int f = i * 256 + tid;
    const int q = f >> 4, seg = (f & 15) * 8;
    *(bf16x8*)&Bs[q * kPA + seg] = *(const bf16x8*)(Bg + (size_t)q * K + seg);
  }
  __syncthreads();

  const int wv = tid >> 6, lane = tid & 63;
  const int lr = lane & 15, lk = (lane >> 4) * 8;

  f32x4 acc[2][4];
#pragma unroll
  for (int i = 0; i < 2; ++i)
#pragma unroll
    for (int j = 0; j < 4; ++j) acc[i][j] = f32x4{0.f, 0.f, 0.f, 0.f};

#pragma unroll
  for (int ks = 0; ks < K; ks += 32) {
    bf16x8 a[2], b[4];
#pragma unroll
    for (int mt = 0; mt < 2; ++mt)
      a[mt] = *(const bf16x8*)(Ag + (size_t)(32 * wv + 16 * mt + lr) * K + ks + lk);
#pragma unroll
    for (int nt = 0; nt < 4; ++nt)
      b[nt] = *(const bf16x8*)&Bs[(16 * nt + lr) * kPA + ks + lk];
#pragma unroll
    for (int mt = 0; mt < 2; ++mt)
#pragma unroll
      for (int nt = 0; nt < 4; ++nt)
        acc[mt][nt] = __builtin_amdgcn_mfma_f32_16x16x32_bf16(
            a[mt], b[nt], acc[mt][nt], 0, 0, 0);
  }

#pragma unroll
  for (int mt = 0; mt < 2; ++mt)
#pragma unroll
    for (int nt = 0; nt < 4; ++nt) {
      const int q = qbase + 16 * nt + lr;
#pragma unroll
      for (int r = 0; r < 4; ++r) {
        const int m = 32 * wv + 16 * mt + 4 * (lane >> 4) + r;
        Out[((size_t)n * kC + m) * kHW + q] = scale * acc[mt][nt][r];
      }
    }
}

// ---------------------------------------------------------------------------
extern "C" void kernel_launch(void* const* d_in, const int* in_sizes, int n_in,
                              void* d_out, int out_size, void* d_ws, size_t ws_size,
                              hipStream_t stream) {
  const float* x   = (const float*)d_in[0];
  const float* p5  = (const float*)d_in[1];
  const float* w6  = (const float*)d_in[2];
  const float* w8  = (const float*)d_in[3];
  const float* w10 = (const float*)d_in[4];
  float* out = (float*)d_out;

  char* ws = (char*)d_ws;                                  // byte offsets
  unsigned short* xT   = (unsigned short*)(ws);            //  9,437,184
  unsigned short* t6b  = (unsigned short*)(ws + 9437184);  //  9,437,184
  unsigned short* part = (unsigned short*)(ws + 18874368); //  9,437,184 (bf16)
  unsigned short* xB   = (unsigned short*)(ws + 28311552); //  9,437,184
  unsigned short* Mb   = (unsigned short*)(ws + 37748736); //    524,288
  float*          t1b  = (float*)(ws + 38273024);          //    147,456
  unsigned short* w6b  = (unsigned short*)(ws + 38420480); //     32,768
  float*          Weff = (float*)(ws + 38453248);          //      7,680
  float*          p5T  = (float*)(ws + 38460928);          //  1,179,648 (end ~39.6 MB)

  const float scale = 1.0f / (sqrtf((float)kC) * sqrtf((float)kHW));

  k_prep<<<120, 256, 0, stream>>>(p5, w6, w10, w8, p5T, w6b, Weff);
  k_xt5t6<<<kN * kH, 256, 0, stream>>>(x, p5T, w6b, xT, xB, t1b, t6b);
  k_corr<<<dim3(kNPC, kN), 256, 0, stream>>>(xB, t1b, Weff, t6b, part);
  k_redM<<<8 * kN, 256, 0, stream>>>(part, Mb);
  k_out<<<dim3(kHW / 64, kN), 256, 0, stream>>>(Mb, xT, out, scale);
}

// Round 12
// 46.975 us; speedup vs baseline: 2.1343x; 1.0148x over previous
//
#include <hip/hip_runtime.h>
#include <cmath>

typedef short bf16x8 __attribute__((ext_vector_type(8)));
typedef short bf16x4 __attribute__((ext_vector_type(4)));
typedef float f32x4 __attribute__((ext_vector_type(4)));

namespace {
constexpr int kN   = 16;
constexpr int kC   = 128;
constexpr int kH   = 48;
constexpr int kW   = 48;
constexpr int kHW  = kH * kW;      // 2304
constexpr int kK9  = 192;          // 3*C/2
constexpr int kNPC = 18;           // correlation p-chunks
constexpr int kPCH = kHW / kNPC;   // 128
constexpr int kLS  = 132;          // LDS row stride (floats) for fp32 transpose tile
constexpr int kPA  = 136;          // bf16 LDS stride (272B, 16B-aligned)
constexpr int kTB  = 40;           // tapB row stride (80B, 16B-aligned)
}

__device__ __forceinline__ unsigned short f2b(float f) {
  unsigned u = __builtin_bit_cast(unsigned, f);
  u = (u + 0x7FFFu + ((u >> 16) & 1u)) >> 16;   // RTNE
  return (unsigned short)u;
}
__device__ __forceinline__ float b2f(unsigned short u) {
  return __builtin_bit_cast(float, ((unsigned)u) << 16);
}

// LDS index for fp32 transpose tile: [w][c] with XOR swizzle on the c-octet.
__device__ __forceinline__ int tidx(int w, int c) {
  return w * kLS + (c ^ (((w >> 2) & 3) << 3));
}

// ---------------------------------------------------------------------------
// Fused prep: blocks 0..47 p5T transpose; 48..111 w6->bf16;
// 112..127 WeffR = bf16(rolled Weff), zero-padded to K=32.
// WeffR[c][t] = bf16( sum_c2 w10[(c-1)&127][3*c2+kk] * w8[c2*5+j] ), t=kk*5+j<15
// ---------------------------------------------------------------------------
__global__ __launch_bounds__(256)
void k_prep(const float* __restrict__ p5, const float* __restrict__ w6,
            const float* __restrict__ w10, const float* __restrict__ w8,
            float* __restrict__ p5T, unsigned short* __restrict__ w6b,
            unsigned short* __restrict__ WeffR) {
  const int tid = threadIdx.x;
  const int bb = blockIdx.x;
  if (bb < 48) {                     // p5T[q][c] = p5[c][q]
    __shared__ float Ls[kW * kLS];
    const int h = bb;
    for (int i = 0; i < 6; ++i) {
      const int idx = i * 256 + tid;
      const int c = idx / 12, s = idx % 12;
      const float4 v = *(const float4*)(p5 + (size_t)c * kHW + h * kW + s * 4);
      const int sw = (s & 3) << 3;
      Ls[(4 * s + 0) * kLS + (c ^ sw)] = v.x;
      Ls[(4 * s + 1) * kLS + (c ^ sw)] = v.y;
      Ls[(4 * s + 2) * kLS + (c ^ sw)] = v.z;
      Ls[(4 * s + 3) * kLS + (c ^ sw)] = v.w;
    }
    __syncthreads();
    for (int i = 0; i < 3; ++i) {
      const int idx = i * 256 + tid;
      const int w = idx >> 4, c = (idx & 15) * 8;
      const float* s = &Ls[tidx(w, c)];
      float4 a{s[0], s[1], s[2], s[3]}, b{s[4], s[5], s[6], s[7]};
      float* dst = p5T + ((size_t)(h * kW + w)) * kC + c;
      *(float4*)dst = a;
      *(float4*)(dst + 4) = b;
    }
  } else if (bb < 112) {             // w6 -> bf16
    const int i = (bb - 48) * 256 + tid;
    w6b[i] = f2b(w6[i]);
  } else {                           // WeffR bf16 rolled, K=32 padded
    const int idx = (bb - 112) * 256 + tid;   // 0..4095
    const int c = idx >> 5, t = idx & 31;
    float s = 0.f;
    if (t < 15) {
      const int o = (c - 1) & (kC - 1);       // channel roll baked in
      const int kk = t / 5, j = t - 5 * kk;
#pragma unroll
      for (int c2 = 0; c2 < 64; ++c2)
        s = fmaf(w10[o * kK9 + 3 * c2 + kk], w8[c2 * 5 + j], s);
    }
    WeffR[idx] = f2b(s);
  }
}

// ---------------------------------------------------------------------------
// Fused transpose + t6 GEMM. One block per (n,h). Linear barrier structure.
// w6 A-fragments direct from global (L2-resident) -> 38.4 KB LDS, 4 blk/CU.
// ---------------------------------------------------------------------------
__global__ __launch_bounds__(256)
void k_xt5t6(const float* __restrict__ x, const float* __restrict__ p5T,
             const unsigned short* __restrict__ w6b,
             unsigned short* __restrict__ xT, unsigned short* __restrict__ xB,
             float* __restrict__ t1, unsigned short* __restrict__ t6) {
  __shared__ __align__(16) float Ls[kW * kLS];             // 25.3 KB
  __shared__ __align__(16) unsigned short t5s[kW * kPA];   // 13.1 KB
  const int b = blockIdx.x;                  // n*48 + h
  const int n = b / kH, h = b - n * kH;
  const int tid = threadIdx.x;
  const float* xrow = x + (size_t)n * kC * kHW + h * kW;
  unsigned short* xBrow = xB + (size_t)n * kC * kHW + h * kW;
  // phase 1: stage x tile (coalesced); emit xB bf16 [c][q]
  for (int i = 0; i < 6; ++i) {
    const int idx = i * 256 + tid;
    const int c = idx / 12, s = idx % 12;
    const float4 v = *(const float4*)(xrow + (size_t)c * kHW + s * 4);
    const int sw = (s & 3) << 3;
    Ls[(4 * s + 0) * kLS + (c ^ sw)] = v.x;
    Ls[(4 * s + 1) * kLS + (c ^ sw)] = v.y;
    Ls[(4 * s + 2) * kLS + (c ^ sw)] = v.z;
    Ls[(4 * s + 3) * kLS + (c ^ sw)] = v.w;
    bf16x4 xb4{(short)f2b(v.x), (short)f2b(v.y), (short)f2b(v.z), (short)f2b(v.w)};
    *(bf16x4*)(xBrow + (size_t)c * kHW + s * 4) = xb4;
  }
  __syncthreads();

  // phase 2: xT + t5s + t1
  for (int i = 0; i < 3; ++i) {
    const int idx = i * 256 + tid;
    const int w = idx >> 4, c = (idx & 15) * 8;
    const int wp = (w == 0) ? (kW - 1) : (w - 1);
    const float* sv = &Ls[tidx(w, c)];
    const float* sp = &Ls[tidx(wp, c)];
    const int q = h * kW + w;
    const float* pv = p5T + (size_t)q * kC + c;

    unsigned short xb[8], tb[8];
    float m = -3.4e38f;
#pragma unroll
    for (int j = 0; j < 8; ++j) {
      const float xv = sv[j];
      const float t5 = pv[j] * fmaxf(-xv, -sp[j]);
      xb[j] = f2b(xv);
      tb[j] = f2b(t5);
      m = fmaxf(m, xv);
    }
    *(bf16x8*)(xT + ((size_t)n * kHW + q) * kC + c) = *(const bf16x8*)xb;
    *(bf16x8*)&t5s[w * kPA + c] = *(const bf16x8*)tb;
#pragma unroll
    for (int off = 1; off < 16; off <<= 1)
      m = fmaxf(m, __shfl_xor(m, off, 16));
    if ((tid & 15) == 0) t1[(size_t)n * kHW + q] = m;
  }
  __syncthreads();

  // phase 3: t6 = w6 @ t5  (m=128 o, n=48 q, k=128 c); A direct from global
  const int wv = tid >> 6, lane = tid & 63;
  const int lr = lane & 15, lk = (lane >> 4) * 8;
  f32x4 acc[2][3];
#pragma unroll
  for (int i = 0; i < 2; ++i)
#pragma unroll
    for (int j = 0; j < 3; ++j) acc[i][j] = f32x4{0.f, 0.f, 0.f, 0.f};
#pragma unroll
  for (int ks = 0; ks < kC; ks += 32) {
    bf16x8 a[2], bf[3];
#pragma unroll
    for (int mt = 0; mt < 2; ++mt)
      a[mt] = *(const bf16x8*)(w6b + (size_t)(32 * wv + 16 * mt + lr) * kC + ks + lk);
#pragma unroll
    for (int nt = 0; nt < 3; ++nt)
      bf[nt] = *(const bf16x8*)&t5s[(16 * nt + lr) * kPA + ks + lk];
#pragma unroll
    for (int mt = 0; mt < 2; ++mt)
#pragma unroll
      for (int nt = 0; nt < 3; ++nt)
        acc[mt][nt] = __builtin_amdgcn_mfma_f32_16x16x32_bf16(a[mt], bf[nt], acc[mt][nt], 0, 0, 0);
  }
#pragma unroll
  for (int mt = 0; mt < 2; ++mt)
#pragma unroll
    for (int nt = 0; nt < 3; ++nt) {
      const int q = h * kW + 16 * nt + lr;
#pragma unroll
      for (int r = 0; r < 4; ++r) {
        const int o = 32 * wv + 16 * mt + 4 * (lane >> 4) + r;
        t6[((size_t)n * kC + o) * kHW + q] = f2b(acc[mt][nt][r]);
      }
    }
}

// ---------------------------------------------------------------------------
// Fused t8..t12 + correlation partials.
// NEW: t10 = WeffR @ taps computed by MFMA (was 245K VALU FMAs/block).
// Linear: stage t1s -> sync -> tapB build -> sync -> conv-MFMA -> t12s
//         -> sync -> max-pass (own octet) -> sync -> main MFMA (B direct t6).
// LDS 47 KB -> 3 blocks/CU.
// ---------------------------------------------------------------------------
__global__ __launch_bounds__(256)
void k_corr(const unsigned short* __restrict__ xB, const float* __restrict__ t1,
            const unsigned short* __restrict__ WeffR, const unsigned short* __restrict__ t6,
            unsigned short* __restrict__ part) {
  __shared__ __align__(16) unsigned short t12s[kC * kPA];   // 34.8 KB
  __shared__ __align__(16) unsigned short tapB[kPCH * kTB]; // 10.2 KB
  __shared__ __align__(16) float t1s[8 * 60];               // 1.9 KB
  const int tid = threadIdx.x;
  const int n = blockIdx.y;
  const int chunk = blockIdx.x;
  const int p0 = chunk * kPCH;
  const int h_lo = p0 / kW;

  // ---- stage t1 window ----
  for (int i = tid; i < 8 * 60; i += 256) {
    const int r = i / 60, cc = i - r * 60;
    const int hh = h_lo - 2 + r, ww = cc - 6;
    t1s[i] = (hh >= 0 && hh < kH && ww >= 0 && ww < kW) ? t1[n * kHW + hh * kW + ww] : 0.f;
  }
  __syncthreads();

  // ---- tapB[p][t] build: t=(kk,j) -> t1s[(r0+2kk)*60 + w + 3j]; pad to 32 ----
  {
    const int p = tid >> 1, o8 = (tid & 1) * 8;
    const int q = p0 + p, h = q / kW, w = q - h * kW, r0 = h - h_lo;
    unsigned short tv[8];
#pragma unroll
    for (int e = 0; e < 8; ++e) {
      const int t = o8 + e;
      float v = 0.f;
      if (t < 15) {
        const int kk = t / 5, j = t - 5 * kk;
        v = t1s[(r0 + 2 * kk) * 60 + w + 3 * j];
      }
      tv[e] = f2b(v);
    }
    *(bf16x8*)&tapB[p * kTB + o8] = *(const bf16x8*)tv;
    const unsigned short z[8] = {0, 0, 0, 0, 0, 0, 0, 0};
    *(bf16x8*)&tapB[p * kTB + 16 + o8] = *(const bf16x8*)z;
  }
  __syncthreads();

  const int wv = tid >> 6, lane = tid & 63;
  const int lr = lane & 15, lk = (lane >> 4) * 8;
  const int wr2 = (wv >> 1) * 64, wc2 = (wv & 1) * 64;

  // ---- conv MFMA: t10[c][p] = WeffR[c][:] . tapB[p][:]  (K=32, 16 MFMA) ----
  {
    f32x4 acc2[4][4];
#pragma unroll
    for (int i = 0; i < 4; ++i)
#pragma unroll
      for (int j = 0; j < 4; ++j) acc2[i][j] = f32x4{0.f, 0.f, 0.f, 0.f};
    bf16x8 a2[4], b2[4];
#pragma unroll
    for (int i = 0; i < 4; ++i) {
      a2[i] = *(const bf16x8*)(WeffR + (size_t)(wr2 + 16 * i + lr) * 32 + lk);
      b2[i] = *(const bf16x8*)&tapB[(wc2 + 16 * i + lr) * kTB + lk];
    }
#pragma unroll
    for (int i = 0; i < 4; ++i)
#pragma unroll
      for (int j = 0; j < 4; ++j)
        acc2[i][j] = __builtin_amdgcn_mfma_f32_16x16x32_bf16(a2[i], b2[j], acc2[i][j], 0, 0, 0);
#pragma unroll
    for (int i = 0; i < 4; ++i)
#pragma unroll
      for (int j = 0; j < 4; ++j)
#pragma unroll
        for (int r = 0; r < 4; ++r)
          t12s[(wr2 + 16 * i + 4 * (lane >> 4) + r) * kPA + wc2 + 16 * j + lr] =
              f2b(acc2[i][j][r]);
  }
  __syncthreads();

  // ---- max pass: t12 = max(x, t10)  (each thread reads+writes OWN octet) ----
  const unsigned short* xn = xB + (size_t)n * kC * kHW;
#pragma unroll
  for (int it = 0; it < 8; ++it) {
    const int idx = it * 256 + tid;
    const int c = idx >> 4, po = (idx & 15) * 8;
    bf16x8 tv = *(bf16x8*)&t12s[c * kPA + po];
    const bf16x8 xv = *(const bf16x8*)(xn + (size_t)c * kHW + p0 + po);
    unsigned short o16[8];
#pragma unroll
    for (int e = 0; e < 8; ++e)
      o16[e] = f2b(fmaxf(b2f((unsigned short)tv[e]), b2f((unsigned short)xv[e])));
    *(bf16x8*)&t12s[c * kPA + po] = *(const bf16x8*)o16;
  }
  __syncthreads();

  // ---- main MFMA: part[c][c'] = sum_p t12[c][p]*t6[c'][p]; B direct global --
  const unsigned short* t6g = t6 + (size_t)n * kC * kHW + p0;
  f32x4 acc[4][4];
#pragma unroll
  for (int i = 0; i < 4; ++i)
#pragma unroll
    for (int j = 0; j < 4; ++j) acc[i][j] = f32x4{0.f, 0.f, 0.f, 0.f};

#pragma unroll
  for (int ks = 0; ks < kPCH; ks += 32) {
    bf16x8 a[4], bv[4];
#pragma unroll
    for (int i = 0; i < 4; ++i) {
      a[i]  = *(const bf16x8*)&t12s[(wr2 + 16 * i + lr) * kPA + ks + lk];
      bv[i] = *(const bf16x8*)(t6g + (size_t)(wc2 + 16 * i + lr) * kHW + ks + lk);
    }
#pragma unroll
    for (int i = 0; i < 4; ++i)
#pragma unroll
      for (int j = 0; j < 4; ++j)
        acc[i][j] = __builtin_amdgcn_mfma_f32_16x16x32_bf16(a[i], bv[j], acc[i][j], 0, 0, 0);
  }

  unsigned short* dst = part + ((size_t)chunk * kN + n) * (kC * kC);
#pragma unroll
  for (int i = 0; i < 4; ++i)
#pragma unroll
    for (int j = 0; j < 4; ++j)
#pragma unroll
      for (int r = 0; r < 4; ++r)
        dst[(wr2 + 16 * i + 4 * (lane >> 4) + r) * kC + wc2 + 16 * j + lr] = f2b(acc[i][j][r]);
}

// ---------------------------------------------------------------------------
// Reduce kNPC bf16 partial slabs -> M bf16 [n][c][c'].  Vectorized bf16x8.
// ---------------------------------------------------------------------------
__global__ __launch_bounds__(256)
void k_redM(const unsigned short* __restrict__ part, unsigned short* __restrict__ M) {
  const int bid = blockIdx.x;                              // 128 blocks
  const int j = bid >> 4, n = bid & 15;
  const int r0 = (j * 256 + threadIdx.x) * 8;              // 0..16383 step 8
  float acc[8];
#pragma unroll
  for (int e = 0; e < 8; ++e) acc[e] = 0.f;
#pragma unroll
  for (int ch = 0; ch < kNPC; ++ch) {
    const bf16x8 v = *(const bf16x8*)(part + (((size_t)ch * kN + n) << 14) + r0);
#pragma unroll
    for (int e = 0; e < 8; ++e) acc[e] += b2f((unsigned short)v[e]);
  }
  unsigned short o16[8];
#pragma unroll
  for (int e = 0; e < 8; ++e) o16[e] = f2b(acc[e]);
  *(bf16x8*)(M + ((size_t)n << 14) + r0) = *(const bf16x8*)o16;
}

// ---------------------------------------------------------------------------
// Final GEMM: out[n,m,q] = scale * sum_k M[n,m,k] * xT[n,q,k].
// A-fragments direct from global (M = 0.5 MB total, cache-hot) -> 17.4 KB LDS.
// ---------------------------------------------------------------------------
__global__ __launch_bounds__(256)
void k_out(const unsigned short* __restrict__ A, const unsigned short* __restrict__ B,
           float* __restrict__ Out, float scale) {
  constexpr int K = 128;
  __shared__ __align__(16) unsigned short Bs[64 * kPA];    // 17.4 KB
  const int tid = threadIdx.x;
  const int n = blockIdx.y;
  const int qbase = blockIdx.x * 64;
  const unsigned short* Ag = A + (size_t)n * kC * K;
  const unsigned short* Bg = B + ((size_t)n * kHW + qbase) * K;

#pragma unroll
  for (int i = 0; i < 4; ++i) {
    const int f = i * 256 + tid;
    const int q = f >> 4, seg = (f & 15) * 8;
    *(bf16x8*)&Bs[q * kPA + seg] = *(const bf16x8*)(Bg + (size_t)q * K + seg);
  }
  __syncthreads();

  const int wv = tid >> 6, lane = tid & 63;
  const int lr = lane & 15, lk = (lane >> 4) * 8;

  f32x4 acc[2][4];
#pragma unroll
  for (int i = 0; i < 2; ++i)
#pragma unroll
    for (int j = 0; j < 4; ++j) acc[i][j] = f32x4{0.f, 0.f, 0.f, 0.f};

#pragma unroll
  for (int ks = 0; ks < K; ks += 32) {
    bf16x8 a[2], b[4];
#pragma unroll
    for (int mt = 0; mt < 2; ++mt)
      a[mt] = *(const bf16x8*)(Ag + (size_t)(32 * wv + 16 * mt + lr) * K + ks + lk);
#pragma unroll
    for (int nt = 0; nt < 4; ++nt)
      b[nt] = *(const bf16x8*)&Bs[(16 * nt + lr) * kPA + ks + lk];
#pragma unroll
    for (int mt = 0; mt < 2; ++mt)
#pragma unroll
      for (int nt = 0; nt < 4; ++nt)
        acc[mt][nt] = __builtin_amdgcn_mfma_f32_16x16x32_bf16(
            a[mt], b[nt], acc[mt][nt], 0, 0, 0);
  }

#pragma unroll
  for (int mt = 0; mt < 2; ++mt)
#pragma unroll
    for (int nt = 0; nt < 4; ++nt) {
      const int q = qbase + 16 * nt + lr;
#pragma unroll
      for (int r = 0; r < 4; ++r) {
        const int m = 32 * wv + 16 * mt + 4 * (lane >> 4) + r;
        Out[((size_t)n * kC + m) * kHW + q] = scale * acc[mt][nt][r];
      }
    }
}

// ---------------------------------------------------------------------------
extern "C" void kernel_launch(void* const* d_in, const int* in_sizes, int n_in,
                              void* d_out, int out_size, void* d_ws, size_t ws_size,
                              hipStream_t stream) {
  const float* x   = (const float*)d_in[0];
  const float* p5  = (const float*)d_in[1];
  const float* w6  = (const float*)d_in[2];
  const float* w8  = (const float*)d_in[3];
  const float* w10 = (const float*)d_in[4];
  float* out = (float*)d_out;

  char* ws = (char*)d_ws;                                   // byte offsets
  unsigned short* xT    = (unsigned short*)(ws);            //  9,437,184
  unsigned short* t6b   = (unsigned short*)(ws + 9437184);  //  9,437,184
  unsigned short* part  = (unsigned short*)(ws + 18874368); //  9,437,184 (bf16)
  unsigned short* xB    = (unsigned short*)(ws + 28311552); //  9,437,184
  unsigned short* Mb    = (unsigned short*)(ws + 37748736); //    524,288
  float*          t1b   = (float*)(ws + 38273024);          //    147,456
  unsigned short* w6b   = (unsigned short*)(ws + 38420480); //     32,768
  unsigned short* WeffR = (unsigned short*)(ws + 38453248); //      8,192
  float*          p5T   = (float*)(ws + 38461440);          //  1,179,648 (end ~39.6 MB)

  const float scale = 1.0f / (sqrtf((float)kC) * sqrtf((float)kHW));

  k_prep<<<128, 256, 0, stream>>>(p5, w6, w10, w8, p5T, w6b, WeffR);
  k_xt5t6<<<kN * kH, 256, 0, stream>>>(x, p5T, w6b, xT, xB, t1b, t6b);
  k_corr<<<dim3(kNPC, kN), 256, 0, stream>>>(xB, t1b, WeffR, t6b, part);
  k_redM<<<8 * kN, 256, 0, stream>>>(part, Mb);
  k_out<<<dim3(kHW / 64, kN), 256, 0, stream>>>(Mb, xT, out, scale);
}

// Round 13
// 46.342 us; speedup vs baseline: 2.1635x; 1.0137x over previous
//
#include <hip/hip_runtime.h>
#include <cmath>

typedef short bf16x8 __attribute__((ext_vector_type(8)));
typedef short bf16x4 __attribute__((ext_vector_type(4)));
typedef float f32x4 __attribute__((ext_vector_type(4)));

namespace {
constexpr int kN   = 16;
constexpr int kC   = 128;
constexpr int kH   = 48;
constexpr int kW   = 48;
constexpr int kHW  = kH * kW;      // 2304
constexpr int kK9  = 192;          // 3*C/2
constexpr int kNPC = 18;           // correlation p-chunks
constexpr int kPCH = kHW / kNPC;   // 128
constexpr int kLS  = 132;          // LDS row stride (floats) for fp32 transpose tile
constexpr int kPA  = 136;          // bf16 LDS stride (272B, 16B-aligned)
constexpr int kTB  = 40;           // tapB row stride (80B, 16B-aligned)
}

__device__ __forceinline__ unsigned short f2b(float f) {
  unsigned u = __builtin_bit_cast(unsigned, f);
  u = (u + 0x7FFFu + ((u >> 16) & 1u)) >> 16;   // RTNE
  return (unsigned short)u;
}
__device__ __forceinline__ float b2f(unsigned short u) {
  return __builtin_bit_cast(float, ((unsigned)u) << 16);
}
__device__ __forceinline__ bf16x8 cvt8(const float* p) {
  const float4 a = *(const float4*)p;
  const float4 b = *(const float4*)(p + 4);
  return bf16x8{(short)f2b(a.x), (short)f2b(a.y), (short)f2b(a.z), (short)f2b(a.w),
                (short)f2b(b.x), (short)f2b(b.y), (short)f2b(b.z), (short)f2b(b.w)};
}

// LDS index for fp32 transpose tile: [w][c] with XOR swizzle on the c-octet.
__device__ __forceinline__ int tidx(int w, int c) {
  return w * kLS + (c ^ (((w >> 2) & 3) << 3));
}

// ---------------------------------------------------------------------------
// Fused transpose + t5 + t6 GEMM + WeffR producer. One block per (n,h).
// Linear barrier chain:
//  p1: x -> Ls (swizzled), emit xB           [Ls write]
//  p2: read Ls -> xT, t1, mx regs            [Ls read]
//  p3: p5 -> Ls (same swizzle)               [Ls write]
//  p4: read Ls -> t5s = p5*mx                [Ls read, t5s write]
//  p5: MFMA t6 = w6 @ t5 (w6 converted on the fly from fp32, L2-hot)
// Blocks 0..15 also emit WeffR (rolled, K=32-padded bf16) for k_corr.
// LDS 38.4 KB -> 4 blocks/CU.
// ---------------------------------------------------------------------------
__global__ __launch_bounds__(256)
void k_xt5t6(const float* __restrict__ x, const float* __restrict__ p5,
             const float* __restrict__ w6, const float* __restrict__ w10,
             const float* __restrict__ w8,
             unsigned short* __restrict__ xT, unsigned short* __restrict__ xB,
             float* __restrict__ t1, unsigned short* __restrict__ t6,
             unsigned short* __restrict__ WeffR) {
  __shared__ __align__(16) float Ls[kW * kLS];             // 25.3 KB
  __shared__ __align__(16) unsigned short t5s[kW * kPA];   // 13.1 KB
  const int b = blockIdx.x;                  // n*48 + h
  const int n = b / kH, h = b - n * kH;
  const int tid = threadIdx.x;

  // WeffR producer: blocks 0..15, one entry per thread (hidden in grid).
  // WeffR[c][t] = bf16( sum_c2 w10[(c-1)&127][3*c2+kk] * w8[c2*5+j] ), t<15.
  if (b < 16) {
    const int idx = b * 256 + tid;           // 0..4095
    const int c = idx >> 5, t = idx & 31;
    float s = 0.f;
    if (t < 15) {
      const int o = (c - 1) & (kC - 1);      // channel roll baked in
      const int kk = t / 5, j = t - 5 * kk;
#pragma unroll
      for (int c2 = 0; c2 < 64; ++c2)
        s = fmaf(w10[o * kK9 + 3 * c2 + kk], w8[c2 * 5 + j], s);
    }
    WeffR[idx] = f2b(s);
  }

  const float* xrow = x + (size_t)n * kC * kHW + h * kW;
  unsigned short* xBrow = xB + (size_t)n * kC * kHW + h * kW;

  // phase 1: stage x tile (coalesced float4); emit xB bf16 [c][q]
#pragma unroll
  for (int i = 0; i < 6; ++i) {
    const int idx = i * 256 + tid;
    const int c = idx / 12, s = idx % 12;
    const float4 v = *(const float4*)(xrow + (size_t)c * kHW + s * 4);
    const int sw = (s & 3) << 3;
    Ls[(4 * s + 0) * kLS + (c ^ sw)] = v.x;
    Ls[(4 * s + 1) * kLS + (c ^ sw)] = v.y;
    Ls[(4 * s + 2) * kLS + (c ^ sw)] = v.z;
    Ls[(4 * s + 3) * kLS + (c ^ sw)] = v.w;
    bf16x4 xb4{(short)f2b(v.x), (short)f2b(v.y), (short)f2b(v.z), (short)f2b(v.w)};
    *(bf16x4*)(xBrow + (size_t)c * kHW + s * 4) = xb4;
  }
  __syncthreads();

  // phase 2: xT + t1 + mx regs (statically indexed)
  float mx[3][8];
#pragma unroll
  for (int i = 0; i < 3; ++i) {
    const int idx = i * 256 + tid;
    const int w = idx >> 4, c = (idx & 15) * 8;
    const int wp = (w == 0) ? (kW - 1) : (w - 1);
    const float* sv = &Ls[tidx(w, c)];
    const float* sp = &Ls[tidx(wp, c)];
    const int q = h * kW + w;

    unsigned short xb[8];
    float m = -3.4e38f;
#pragma unroll
    for (int j = 0; j < 8; ++j) {
      const float xv = sv[j];
      mx[i][j] = fmaxf(-xv, -sp[j]);
      xb[j] = f2b(xv);
      m = fmaxf(m, xv);
    }
    *(bf16x8*)(xT + ((size_t)n * kHW + q) * kC + c) = *(const bf16x8*)xb;
#pragma unroll
    for (int off = 1; off < 16; off <<= 1)
      m = fmaxf(m, __shfl_xor(m, off, 16));
    if ((tid & 15) == 0) t1[(size_t)n * kHW + q] = m;
  }
  __syncthreads();

  // phase 3: stage p5 tile into Ls (same swizzle; p5 is batch-free [c][q])
#pragma unroll
  for (int i = 0; i < 6; ++i) {
    const int idx = i * 256 + tid;
    const int c = idx / 12, s = idx % 12;
    const float4 v = *(const float4*)(p5 + (size_t)c * kHW + h * kW + s * 4);
    const int sw = (s & 3) << 3;
    Ls[(4 * s + 0) * kLS + (c ^ sw)] = v.x;
    Ls[(4 * s + 1) * kLS + (c ^ sw)] = v.y;
    Ls[(4 * s + 2) * kLS + (c ^ sw)] = v.z;
    Ls[(4 * s + 3) * kLS + (c ^ sw)] = v.w;
  }
  __syncthreads();

  // phase 4: t5s[w][c] = bf16( p5[q][c] * mx )
#pragma unroll
  for (int i = 0; i < 3; ++i) {
    const int idx = i * 256 + tid;
    const int w = idx >> 4, c = (idx & 15) * 8;
    const float* pv = &Ls[tidx(w, c)];
    unsigned short tb[8];
#pragma unroll
    for (int j = 0; j < 8; ++j) tb[j] = f2b(pv[j] * mx[i][j]);
    *(bf16x8*)&t5s[w * kPA + c] = *(const bf16x8*)tb;
  }
  __syncthreads();

  // phase 5: t6 = w6 @ t5  (m=128 o, n=48 q, k=128 c); w6 converted in-flight
  const int wv = tid >> 6, lane = tid & 63;
  const int lr = lane & 15, lk = (lane >> 4) * 8;
  f32x4 acc[2][3];
#pragma unroll
  for (int i = 0; i < 2; ++i)
#pragma unroll
    for (int j = 0; j < 3; ++j) acc[i][j] = f32x4{0.f, 0.f, 0.f, 0.f};
#pragma unroll
  for (int ks = 0; ks < kC; ks += 32) {
    bf16x8 a[2], bf[3];
#pragma unroll
    for (int mt = 0; mt < 2; ++mt)
      a[mt] = cvt8(w6 + (size_t)(32 * wv + 16 * mt + lr) * kC + ks + lk);
#pragma unroll
    for (int nt = 0; nt < 3; ++nt)
      bf[nt] = *(const bf16x8*)&t5s[(16 * nt + lr) * kPA + ks + lk];
#pragma unroll
    for (int mt = 0; mt < 2; ++mt)
#pragma unroll
      for (int nt = 0; nt < 3; ++nt)
        acc[mt][nt] = __builtin_amdgcn_mfma_f32_16x16x32_bf16(a[mt], bf[nt], acc[mt][nt], 0, 0, 0);
  }
#pragma unroll
  for (int mt = 0; mt < 2; ++mt)
#pragma unroll
    for (int nt = 0; nt < 3; ++nt) {
      const int q = h * kW + 16 * nt + lr;
#pragma unroll
      for (int r = 0; r < 4; ++r) {
        const int o = 32 * wv + 16 * mt + 4 * (lane >> 4) + r;
        t6[((size_t)n * kC + o) * kHW + q] = f2b(acc[mt][nt][r]);
      }
    }
}

// ---------------------------------------------------------------------------
// Fused t8..t12 + correlation partials. t10 via MFMA (WeffR @ taps).
// Linear: stage t1s -> sync -> tapB -> sync -> conv-MFMA -> t12s
//         -> sync -> max-pass (own octet) -> sync -> main MFMA (B direct t6).
// ---------------------------------------------------------------------------
__global__ __launch_bounds__(256)
void k_corr(const unsigned short* __restrict__ xB, const float* __restrict__ t1,
            const unsigned short* __restrict__ WeffR, const unsigned short* __restrict__ t6,
            unsigned short* __restrict__ part) {
  __shared__ __align__(16) unsigned short t12s[kC * kPA];   // 34.8 KB
  __shared__ __align__(16) unsigned short tapB[kPCH * kTB]; // 10.2 KB
  __shared__ __align__(16) float t1s[8 * 60];               // 1.9 KB
  const int tid = threadIdx.x;
  const int n = blockIdx.y;
  const int chunk = blockIdx.x;
  const int p0 = chunk * kPCH;
  const int h_lo = p0 / kW;

  for (int i = tid; i < 8 * 60; i += 256) {
    const int r = i / 60, cc = i - r * 60;
    const int hh = h_lo - 2 + r, ww = cc - 6;
    t1s[i] = (hh >= 0 && hh < kH && ww >= 0 && ww < kW) ? t1[n * kHW + hh * kW + ww] : 0.f;
  }
  __syncthreads();

  // tapB[p][t]: t=(kk,j) -> t1s[(r0+2kk)*60 + w + 3j]; zero-pad to 32
  {
    const int p = tid >> 1, o8 = (tid & 1) * 8;
    const int q = p0 + p, h = q / kW, w = q - h * kW, r0 = h - h_lo;
    unsigned short tv[8];
#pragma unroll
    for (int e = 0; e < 8; ++e) {
      const int t = o8 + e;
      float v = 0.f;
      if (t < 15) {
        const int kk = t / 5, j = t - 5 * kk;
        v = t1s[(r0 + 2 * kk) * 60 + w + 3 * j];
      }
      tv[e] = f2b(v);
    }
    *(bf16x8*)&tapB[p * kTB + o8] = *(const bf16x8*)tv;
    const unsigned short z[8] = {0, 0, 0, 0, 0, 0, 0, 0};
    *(bf16x8*)&tapB[p * kTB + 16 + o8] = *(const bf16x8*)z;
  }
  __syncthreads();

  const int wv = tid >> 6, lane = tid & 63;
  const int lr = lane & 15, lk = (lane >> 4) * 8;
  const int wr2 = (wv >> 1) * 64, wc2 = (wv & 1) * 64;

  // conv MFMA: t10[c][p] = WeffR[c][:] . tapB[p][:]  (K=32)
  {
    f32x4 acc2[4][4];
#pragma unroll
    for (int i = 0; i < 4; ++i)
#pragma unroll
      for (int j = 0; j < 4; ++j) acc2[i][j] = f32x4{0.f, 0.f, 0.f, 0.f};
    bf16x8 a2[4], b2[4];
#pragma unroll
    for (int i = 0; i < 4; ++i) {
      a2[i] = *(const bf16x8*)(WeffR + (size_t)(wr2 + 16 * i + lr) * 32 + lk);
      b2[i] = *(const bf16x8*)&tapB[(wc2 + 16 * i + lr) * kTB + lk];
    }
#pragma unroll
    for (int i = 0; i < 4; ++i)
#pragma unroll
      for (int j = 0; j < 4; ++j)
        acc2[i][j] = __builtin_amdgcn_mfma_f32_16x16x32_bf16(a2[i], b2[j], acc2[i][j], 0, 0, 0);
#pragma unroll
    for (int i = 0; i < 4; ++i)
#pragma unroll
      for (int j = 0; j < 4; ++j)
#pragma unroll
        for (int r = 0; r < 4; ++r)
          t12s[(wr2 + 16 * i + 4 * (lane >> 4) + r) * kPA + wc2 + 16 * j + lr] =
              f2b(acc2[i][j][r]);
  }
  __syncthreads();

  // max pass: t12 = max(x, t10) (each thread reads+writes OWN octet)
  const unsigned short* xn = xB + (size_t)n * kC * kHW;
#pragma unroll
  for (int it = 0; it < 8; ++it) {
    const int idx = it * 256 + tid;
    const int c = idx >> 4, po = (idx & 15) * 8;
    bf16x8 tv = *(bf16x8*)&t12s[c * kPA + po];
    const bf16x8 xv = *(const bf16x8*)(xn + (size_t)c * kHW + p0 + po);
    unsigned short o16[8];
#pragma unroll
    for (int e = 0; e < 8; ++e)
      o16[e] = f2b(fmaxf(b2f((unsigned short)tv[e]), b2f((unsigned short)xv[e])));
    *(bf16x8*)&t12s[c * kPA + po] = *(const bf16x8*)o16;
  }
  __syncthreads();

  // main MFMA: part[c][c'] = sum_p t12[c][p]*t6[c'][p]; B direct from global
  const unsigned short* t6g = t6 + (size_t)n * kC * kHW + p0;
  f32x4 acc[4][4];
#pragma unroll
  for (int i = 0; i < 4; ++i)
#pragma unroll
    for (int j = 0; j < 4; ++j) acc[i][j] = f32x4{0.f, 0.f, 0.f, 0.f};

#pragma unroll
  for (int ks = 0; ks < kPCH; ks += 32) {
    bf16x8 a[4], bv[4];
#pragma unroll
    for (int i = 0; i < 4; ++i) {
      a[i]  = *(const bf16x8*)&t12s[(wr2 + 16 * i + lr) * kPA + ks + lk];
      bv[i] = *(const bf16x8*)(t6g + (size_t)(wc2 + 16 * i + lr) * kHW + ks + lk);
    }
#pragma unroll
    for (int i = 0; i < 4; ++i)
#pragma unroll
      for (int j = 0; j < 4; ++j)
        acc[i][j] = __builtin_amdgcn_mfma_f32_16x16x32_bf16(a[i], bv[j], acc[i][j], 0, 0, 0);
  }

  unsigned short* dst = part + ((size_t)chunk * kN + n) * (kC * kC);
#pragma unroll
  for (int i = 0; i < 4; ++i)
#pragma unroll
    for (int j = 0; j < 4; ++j)
#pragma unroll
      for (int r = 0; r < 4; ++r)
        dst[(wr2 + 16 * i + 4 * (lane >> 4) + r) * kC + wc2 + 16 * j + lr] = f2b(acc[i][j][r]);
}

// ---------------------------------------------------------------------------
// Reduce kNPC bf16 partial slabs -> M bf16 [n][c][c'].  Vectorized bf16x8.
// ---------------------------------------------------------------------------
__global__ __launch_bounds__(256)
void k_redM(const unsigned short* __restrict__ part, unsigned short* __restrict__ M) {
  const int bid = blockIdx.x;                              // 128 blocks
  const int j = bid >> 4, n = bid & 15;
  const int r0 = (j * 256 + threadIdx.x) * 8;              // 0..16383 step 8
  float acc[8];
#pragma unroll
  for (int e = 0; e < 8; ++e) acc[e] = 0.f;
#pragma unroll
  for (int ch = 0; ch < kNPC; ++ch) {
    const bf16x8 v = *(const bf16x8*)(part + (((size_t)ch * kN + n) << 14) + r0);
#pragma unroll
    for (int e = 0; e < 8; ++e) acc[e] += b2f((unsigned short)v[e]);
  }
  unsigned short o16[8];
#pragma unroll
  for (int e = 0; e < 8; ++e) o16[e] = f2b(acc[e]);
  *(bf16x8*)(M + ((size_t)n << 14) + r0) = *(const bf16x8*)o16;
}

// ---------------------------------------------------------------------------
// Final GEMM: out[n,m,q] = scale * sum_k M[n,m,k] * xT[n,q,k].
// A-fragments direct from global (M = 0.5 MB total, cache-hot) -> 17.4 KB LDS.
// ---------------------------------------------------------------------------
__global__ __launch_bounds__(256)
void k_out(const unsigned short* __restrict__ A, const unsigned short* __restrict__ B,
           float* __restrict__ Out, float scale) {
  constexpr int K = 128;
  __shared__ __align__(16) unsigned short Bs[64 * kPA];    // 17.4 KB
  const int tid = threadIdx.x;
  const int n = blockIdx.y;
  const int qbase = blockIdx.x * 64;
  const unsigned short* Ag = A + (size_t)n * kC * K;
  const unsigned short* Bg = B + ((size_t)n * kHW + qbase) * K;

#pragma unroll
  for (int i = 0; i < 4; ++i) {
    const int f = i * 256 + tid;
    const int q = f >> 4, seg = (f & 15) * 8;
    *(bf16x8*)&Bs[q * kPA + seg] = *(const bf16x8*)(Bg + (size_t)q * K + seg);
  }
  __syncthreads();

  const int wv = tid >> 6, lane = tid & 63;
  const int lr = lane & 15, lk = (lane >> 4) * 8;

  f32x4 acc[2][4];
#pragma unroll
  for (int i = 0; i < 2; ++i)
#pragma unroll
    for (int j = 0; j < 4; ++j) acc[i][j] = f32x4{0.f, 0.f, 0.f, 0.f};

#pragma unroll
  for (int ks = 0; ks < K; ks += 32) {
    bf16x8 a[2], b[4];
#pragma unroll
    for (int mt = 0; mt < 2; ++mt)
      a[mt] = *(const bf16x8*)(Ag + (size_t)(32 * wv + 16 * mt + lr) * K + ks + lk);
#pragma unroll
    for (int nt = 0; nt < 4; ++nt)
      b[nt] = *(const bf16x8*)&Bs[(16 * nt + lr) * kPA + ks + lk];
#pragma unroll
    for (int mt = 0; mt < 2; ++mt)
#pragma unroll
      for (int nt = 0; nt < 4; ++nt)
        acc[mt][nt] = __builtin_amdgcn_mfma_f32_16x16x32_bf16(
            a[mt], b[nt], acc[mt][nt], 0, 0, 0);
  }

#pragma unroll
  for (int mt = 0; mt < 2; ++mt)
#pragma unroll
    for (int nt = 0; nt < 4; ++nt) {
      const int q = qbase + 16 * nt + lr;
#pragma unroll
      for (int r = 0; r < 4; ++r) {
        const int m = 32 * wv + 16 * mt + 4 * (lane >> 4) + r;
        Out[((size_t)n * kC + m) * kHW + q] = scale * acc[mt][nt][r];
      }
    }
}

// ---------------------------------------------------------------------------
extern "C" void kernel_launch(void* const* d_in, const int* in_sizes, int n_in,
                              void* d_out, int out_size, void* d_ws, size_t ws_size,
                              hipStream_t stream) {
  const float* x   = (const float*)d_in[0];
  const float* p5  = (const float*)d_in[1];
  const float* w6  = (const float*)d_in[2];
  const float* w8  = (const float*)d_in[3];
  const float* w10 = (const float*)d_in[4];
  float* out = (float*)d_out;

  char* ws = (char*)d_ws;                                   // byte offsets
  unsigned short* xT    = (unsigned short*)(ws);            //  9,437,184
  unsigned short* t6b   = (unsigned short*)(ws + 9437184);  //  9,437,184
  unsigned short* part  = (unsigned short*)(ws + 18874368); //  9,437,184 (bf16)
  unsigned short* xB    = (unsigned short*)(ws + 28311552); //  9,437,184
  unsigned short* Mb    = (unsigned short*)(ws + 37748736); //    524,288
  float*          t1b   = (float*)(ws + 38273024);          //    147,456
  unsigned short* WeffR = (unsigned short*)(ws + 38420480); //      8,192 (end ~38.4 MB)

  const float scale = 1.0f / (sqrtf((float)kC) * sqrtf((float)kHW));

  k_xt5t6<<<kN * kH, 256, 0, stream>>>(x, p5, w6, w10, w8, xT, xB, t1b, t6b, WeffR);
  k_corr<<<dim3(kNPC, kN), 256, 0, stream>>>(xB, t1b, WeffR, t6b, part);
  k_redM<<<8 * kN, 256, 0, stream>>>(part, Mb);
  k_out<<<dim3(kHW / 64, kN), 256, 0, stream>>>(Mb, xT, out, scale);
}